// Round 6
// baseline (704.237 us; speedup 1.0000x reference)
//
#include <hip/hip_runtime.h>
#include <hip/hip_bf16.h>
#include <math.h>

// ============================================================================
// MinimalNetwork, round 6: all global writes coalesced.
//   radial_hidden : h_bf[e][136] bf16 — layer3 staged in LDS, float4 copy-out
//   prep_w3t      : W3t[1216][136] bf16, chunk-major column permutation
//   fused_kernel  : 19 phases (stage W3 chunk -> kv=C3*y -> MFMA 64x64 ->
//                   LDS(sRt pitch 68) -> 4-role TP consume) -> quad-merge ->
//                   sMsg in LDS -> coalesced float4 stream to msg[e][72]
//   hist/scan/fill: CSR of edges by target node
//   gather_kernel : one wave per node, sums its message rows -> out
// ============================================================================

#define FEATD 72
#define NCOL 1216
#define SWISH_SCALE 1.679177f

typedef __attribute__((ext_vector_type(8))) short bf16x8;
typedef __attribute__((ext_vector_type(4))) float f32x4;

// ---- 19 (lo,li,lf) chunks; CB_OFF = offsets into the C3 coefficient pool ----
constexpr int NCOMBO = 19;
constexpr int CB_LO[NCOMBO] = {0,0,0,1,1,1,1,1,1,1,2,2,2,2,2,2,2,2,2};
constexpr int CB_LI[NCOMBO] = {0,1,2,0,1,1,1,2,2,2,0,1,1,1,2,2,2,2,2};
constexpr int CB_LF[NCOMBO] = {0,1,2,1,0,1,2,1,2,3,2,1,2,3,0,1,2,3,4};
constexpr int CB_OFF[NCOMBO] = {0,1,10,35,44,53,80,125,170,245,350,375,420,495,600,625,700,825,1000};
constexpr int CB_SZ[NCOMBO]  = {1,9,25,9,9,27,45,45,75,105,25,45,75,105,25,75,125,175,225};
constexpr int C3TOT = 1225;

constexpr int C3OFFT[3][3][5] = {
  { {0,-1,-1,-1,-1}, {-1,1,-1,-1,-1}, {-1,-1,10,-1,-1} },
  { {-1,35,-1,-1,-1}, {44,53,80,-1,-1}, {-1,125,170,245,-1} },
  { {-1,-1,350,-1,-1}, {-1,375,420,495,-1}, {600,625,700,825,1000} }
};
constexpr int ROFFT[3][3] = {{0,64,128},{192,256,448},{640,704,896}};
constexpr int FOFFT[3]   = {0,8,32};

__device__ const double d_fact[11] = {1.,1.,2.,6.,24.,120.,720.,5040.,40320.,362880.,3628800.};

// ---------------------------------------------------------------------------
// Wigner 3j (complex basis, Racah) in double precision + real change of basis
// ---------------------------------------------------------------------------
__device__ double w3j_entry(int j1,int j2,int j3,int m1,int m2,int m3){
  if (m1+m2+m3 != 0) return 0.0;
  int dj = j1-j2; if (dj<0) dj=-dj;
  if (j3 < dj || j3 > j1+j2) return 0.0;
  int t1 = j2 - m1 - j3, t2 = j1 + m2 - j3;
  int kmin = 0; if (t1>kmin) kmin=t1; if (t2>kmin) kmin=t2;
  int kmax = j1+j2-j3; if (j1-m1<kmax) kmax=j1-m1; if (j2+m2<kmax) kmax=j2+m2;
  double s = 0.0;
  for (int k=kmin;k<=kmax;++k){
    double den = d_fact[k]*d_fact[k-t1]*d_fact[k-t2]*d_fact[j1+j2-j3-k]
               * d_fact[j1-m1-k]*d_fact[j2+m2-k];
    s += ((k&1)? -1.0:1.0)/den;
  }
  double pref = sqrt(d_fact[j1+j2-j3]*d_fact[j1-j2+j3]*d_fact[-j1+j2+j3]/d_fact[j1+j2+j3+1]
               * d_fact[j1+m1]*d_fact[j1-m1]*d_fact[j2+m2]*d_fact[j2-m2]
               * d_fact[j3+m3]*d_fact[j3-m3]);
  int ex = j1-j2-m3;
  if (ex & 1) pref = -pref;
  return pref*s;
}

__device__ void cob(int l, int r, int c, double& re, double& im){
  re = 0.0; im = 0.0;
  int mr = r - l, mc = c - l;
  const double s = 0.70710678118654752440;
  if (mr == 0) { if (mc == 0) re = 1.0; return; }
  if (mr > 0) {
    if (mc == mr)       re = (mr & 1) ? -s : s;
    else if (mc == -mr) re = s;
  } else {
    int m = -mr;
    if (mc == -m)      im = s;
    else if (mc == m)  im = (m & 1) ? s : -s;
  }
}

__global__ void c3_build_kernel(double* __restrict__ Tre, double* __restrict__ Tim){
  int idx = blockIdx.x*64 + threadIdx.x;
  if (idx >= C3TOT) return;
  int c = 0;
  while (c+1 < NCOMBO && idx >= CB_OFF[c+1]) ++c;
  int lo = CB_LO[c], li = CB_LI[c], lf = CB_LF[c];
  int n2 = 2*li+1, n3 = 2*lf+1;
  int loc = idx - CB_OFF[c];
  int a = loc/(n2*n3), b = (loc/n3)%n2, g = loc%n3;
  double sre=0.0, sim=0.0;
  for (int m1=-lo; m1<=lo; ++m1){
    for (int m2=-li; m2<=li; ++m2){
      int m3 = -m1-m2;
      if (m3 < -lf || m3 > lf) continue;
      double w = w3j_entry(lo,li,lf,m1,m2,m3);
      if (w == 0.0) continue;
      double r1,i1,r2,i2,r3,i3;
      cob(lo, a, m1+lo, r1,i1);
      cob(li, b, m2+li, r2,i2);
      cob(lf, g, m3+lf, r3,i3);
      double rr = r1*r2 - i1*i2, ri = r1*i2 + i1*r2;
      double fr = rr*r3 - ri*i3, fi = rr*i3 + ri*r3;
      sre += fr*w; sim += fi*w;
    }
  }
  Tre[idx] = sre; Tim[idx] = sim;
}

__global__ void c3_norm_kernel(const double* __restrict__ Tre, const double* __restrict__ Tim,
                               float* __restrict__ C3f){
  int c = blockIdx.x;
  int off = CB_OFF[c], sz = CB_SZ[c];
  int t = threadIdx.x;
  double sre=0.0, sim=0.0;
  for (int p=t; p<sz; p+=64){ double x=Tre[off+p], y=Tim[off+p]; sre+=x*x; sim+=y*y; }
  for (int m=1; m<64; m<<=1){ sre += __shfl_xor(sre, m, 64); sim += __shfl_xor(sim, m, 64); }
  bool useRe = (sre >= sim);
  double n = sqrt(useRe ? sre : sim);
  double inv = (n > 0.0) ? 1.0/n : 1.0;
  for (int p=t; p<sz; p+=64){
    double v = useRe ? Tre[off+p] : Tim[off+p];
    C3f[off+p] = (float)(v*inv);
  }
}

// ---------------------------------------------------------------------------
// W3t[c'][k], c' chunk-major: c' = chunk*64 + uv maps to original column
// ROFFT[lo][li] + uv*nlf + fi. 0.1 scale folded. Pitch 136, pad k>=100 = 0.
// ---------------------------------------------------------------------------
__global__ __launch_bounds__(256) void prep_w3t_kernel(const float* __restrict__ W3,
                                                       __hip_bfloat16* __restrict__ W3t){
  int idx = blockIdx.x*256 + threadIdx.x;
  if (idx >= 1216*136) return;
  int cp = idx/136, k = idx%136;
  int chunk = cp>>6, uv = cp&63;
  int lo = CB_LO[chunk], li = CB_LI[chunk], lf = CB_LF[chunk];
  int lmin = lo<li ? lo : li;
  int nlf = 2*lmin+1;
  int fi = lf - (lo>li ? lo-li : li-lo);
  int c = ROFFT[lo][li] + uv*nlf + fi;
  float v = (k < 100) ? 0.1f*W3[(size_t)k*NCOL + c] : 0.f;
  W3t[idx] = __float2bfloat16(v);
}

// ---------------------------------------------------------------------------
// Radial hidden chain -> h_bf[e][136] bf16; layer3 staged in LDS, coalesced out
// ---------------------------------------------------------------------------
__device__ __forceinline__ float swishf(float s){
  return SWISH_SCALE * s / (1.f + __expf(-s));
}

__global__ __launch_bounds__(256) void radial_hidden_kernel(
    const float* __restrict__ radii,
    const float* __restrict__ W0, const float* __restrict__ W1, const float* __restrict__ W2,
    __hip_bfloat16* __restrict__ h_bf, int E)
{
  __shared__ float sW[10000];
  __shared__ __align__(16) float sX[6400];   // [er][k], pitch 100; reused as bf16 staging
  __shared__ float sY[6400];
  __shared__ float sbas[640];
  const int t = threadIdx.x;
  const int et0 = blockIdx.x*64;

  for (int p=t; p<640; p+=256){
    int er = p/10, k = p%10;
    int eg = et0 + er;
    float r = (eg < E) ? radii[eg] : 0.f;
    float c = 0.7f + (2.5f/9.0f)*(float)k;
    float d = (r - c) * (9.0f/2.5f);
    sbas[p] = __expf(-d*d);
  }
  for (int p=t; p<1000; p+=256) sW[p] = W0[p]*0.3162277660168379f; // 1/sqrt(10)
  __syncthreads();
  for (int p=t; p<6400; p+=256){
    int er = p/100, o = p%100;
    float s = 0.f;
    #pragma unroll
    for (int k=0;k<10;++k) s += sbas[er*10+k]*sW[k*100+o];
    sX[p] = swishf(s);
  }
  __syncthreads();
  for (int p=t; p<10000; p+=256) sW[p] = W1[p]*0.1f;
  __syncthreads();
  for (int q=t; q<400; q+=256){
    int erb = (q/25)*4, ob = (q%25)*4;
    float acc[4][4] = {};
    for (int k=0;k<100;++k){
      float4 w = *(const float4*)&sW[k*100+ob];
      #pragma unroll
      for (int i=0;i<4;++i){
        float a = sX[(erb+i)*100+k];
        acc[i][0]+=a*w.x; acc[i][1]+=a*w.y; acc[i][2]+=a*w.z; acc[i][3]+=a*w.w;
      }
    }
    #pragma unroll
    for (int i=0;i<4;++i){
      float4 v = make_float4(swishf(acc[i][0]),swishf(acc[i][1]),swishf(acc[i][2]),swishf(acc[i][3]));
      *(float4*)&sY[(erb+i)*100+ob] = v;
    }
  }
  __syncthreads();   // layer2 done reading sX -> sX reusable as staging
  for (int p=t; p<10000; p+=256) sW[p] = W2[p]*0.1f;
  __syncthreads();

  // layer 3: compute into LDS staging (bf16 [64][136]), then coalesced copy-out
  __hip_bfloat16* sHB = (__hip_bfloat16*)sX;   // 17408 B <= 25600 B
  for (int p=t; p<64*36; p+=256){
    int er = p/36, k = 100 + p%36;
    sHB[er*136 + k] = __float2bfloat16(0.f);
  }
  for (int q=t; q<400; q+=256){
    int erb = (q/25)*4, ob = (q%25)*4;
    float acc[4][4] = {};
    for (int k=0;k<100;++k){
      float4 w = *(const float4*)&sW[k*100+ob];
      #pragma unroll
      for (int i=0;i<4;++i){
        float a = sY[(erb+i)*100+k];
        acc[i][0]+=a*w.x; acc[i][1]+=a*w.y; acc[i][2]+=a*w.z; acc[i][3]+=a*w.w;
      }
    }
    #pragma unroll
    for (int i=0;i<4;++i){
      __hip_bfloat16 hv[4];
      #pragma unroll
      for (int j=0;j<4;++j) hv[j] = __float2bfloat16(swishf(acc[i][j]));
      *(short4*)&sHB[(erb+i)*136 + ob] = *(short4*)hv;
    }
  }
  __syncthreads();
  {
    const float4* sm = (const float4*)sHB;
    float4* gm = (float4*)(h_bf + (size_t)et0*136);
    for (int p=t; p<1088; p+=256) gm[p] = sm[p];
  }
}

// ---------------------------------------------------------------------------
// CSR of edges by target node
// ---------------------------------------------------------------------------
__global__ __launch_bounds__(256) void hist_kernel(const int* __restrict__ ei,
                                                   int* __restrict__ deg, int E){
  int e = blockIdx.x*256 + threadIdx.x;
  if (e < E) atomicAdd(&deg[ei[E+e]], 1);
}

__global__ __launch_bounds__(256) void scan_kernel(const int* __restrict__ deg,
                                                   int* __restrict__ off,
                                                   int* __restrict__ cursor, int N, int E){
  __shared__ int part[256], spref[256];
  const int t = threadIdx.x;
  const int CH = (N + 255)/256;
  int lo = t*CH, hi = lo+CH < N ? lo+CH : N;
  int s = 0;
  for (int n=lo; n<hi; ++n) s += deg[n];
  part[t] = s;
  __syncthreads();
  if (t == 0){
    int run = 0;
    for (int i=0;i<256;++i){ spref[i] = run; run += part[i]; }
  }
  __syncthreads();
  int run = spref[t];
  for (int n=lo; n<hi; ++n){ off[n] = run; cursor[n] = run; run += deg[n]; }
  if (t == 255) off[N] = E;
}

__global__ __launch_bounds__(256) void fill_kernel(const int* __restrict__ ei,
                                                   int* __restrict__ cursor,
                                                   int* __restrict__ eid, int E){
  int e = blockIdx.x*256 + threadIdx.x;
  if (e < E){
    int idx = atomicAdd(&cursor[ei[E+e]], 1);
    eid[idx] = e;
  }
}

// ---------------------------------------------------------------------------
// Gather: one 64-lane wave per node; writes every output element exactly once.
// ---------------------------------------------------------------------------
__global__ __launch_bounds__(64) void gather_kernel(const float* __restrict__ msg,
                                                    const int* __restrict__ off,
                                                    const int* __restrict__ eid,
                                                    float* __restrict__ out, int N){
  const int n = blockIdx.x;
  const int t = threadIdx.x;
  const int s = off[n], e1 = off[n+1];
  float a0 = 0.f, a1 = 0.f;
  for (int i=s; i<e1; ++i){
    const float* m = msg + (size_t)eid[i]*FEATD;
    a0 += m[t];
    if (t < 8) a1 += m[64+t];
  }
  out[(size_t)n*FEATD + t] = a0;
  if (t < 8) out[(size_t)n*FEATD + 64 + t] = a1;
}

// ---------------------------------------------------------------------------
// Fused GEMM+TP. 256 threads = 4 waves; 64 edges/block; 4 roles/edge.
// Hand-partitioned LDS pool so the epilogue can alias sMsg over sH+sW3.
// ---------------------------------------------------------------------------
#define RTP 68   // sRt pitch (68 mod 32 = 4 -> 2-way max on role-strided reads)

constexpr int OF_H   = 0;         // 64*136 bf16 = 17408
constexpr int OF_W3  = 17408;     // 64*136 bf16 = 17408
constexpr int OF_RT  = 34816;     // 64*68 f32   = 17408
constexpr int OF_F   = 52224;     // 64*74 bf16  = 9472
constexpr int OF_RSH = 61696;     // 64*26 f32   = 6656
constexpr int OF_KV  = 68352;     // 64*26 f32   = 6656
constexpr int OF_C3  = 75008;     // 1228 f32    = 4912
constexpr int OF_SRC = 79920;     // 64 int      = 256
constexpr int SMEM_SZ = 80176;

template<int LO,int LI,int LF>
__device__ __forceinline__ void phase(
    int chunk, const __hip_bfloat16* __restrict__ W3t,
    __hip_bfloat16* sH, __hip_bfloat16* sW3, float* sRt,
    __hip_bfloat16* sF, float* sRsh, float* sKV, const float* sC3,
    float (&acc)[8][9], int t)
{
  constexpr int NO = 2*LO+1, NI = 2*LI+1, NF = 2*LF+1;
  constexpr int C3B = C3OFFT[LO][LI][LF];
  constexpr int FO  = FOFFT[LI];
  constexpr int AO  = (LO==0) ? 0 : (LO==1) ? 1 : 4;

  __syncthreads();   // [A] prev phase's consume done (sKV/sRt/sW3 free)

  // ---- stage this chunk's 64 W3t rows (17408 B) ----
  {
    const float4* g = (const float4*)(W3t + (size_t)chunk*64*136);
    float4* s = (float4*)sW3;
    for (int p=t; p<1088; p+=256) s[p] = g[p];
  }
  // ---- cooperative kv[e][o*NI+mi] = sum_mf C3 * y ----
  {
    const int le = t & 63, wv = t >> 6;
    float y[NF];
    #pragma unroll
    for (int mf=0; mf<NF; ++mf) y[mf] = sRsh[le*26 + LF*LF + mf];
    for (int it = wv; it < NO*NI; it += 4){
      float s = 0.f;
      #pragma unroll
      for (int mf=0; mf<NF; ++mf) s += sC3[C3B + it*NF + mf] * y[mf];
      sKV[le*26 + it] = s;
    }
  }
  __syncthreads();   // [B] sW3 + sKV visible

  // ---- MFMA: Rt_chunk[c=uv][e], 64x64, K=128; each wave does 16 edges ----
  {
    const int lane = t & 63, wv = t >> 6;
    const int lr = lane & 15, lq = lane >> 4;
    f32x4 a4[4] = {};
    #pragma unroll
    for (int ks=0; ks<4; ++ks){
      bf16x8 b = *(const bf16x8*)&sH[(wv*16+lr)*136 + ks*32 + lq*8];
      #pragma unroll
      for (int ct=0; ct<4; ++ct){
        bf16x8 a = *(const bf16x8*)&sW3[(ct*16+lr)*136 + ks*32 + lq*8];
        a4[ct] = __builtin_amdgcn_mfma_f32_16x16x32_bf16(a, b, a4[ct], 0, 0, 0);
      }
    }
    #pragma unroll
    for (int ct=0; ct<4; ++ct)
      #pragma unroll
      for (int r=0; r<4; ++r)
        sRt[(ct*16 + lq*4 + r)*RTP + wv*16 + lr] = a4[ct][r];
  }
  __syncthreads();   // [C] sRt visible

  // ---- TP consume: 4 roles/edge, role handles v in {2*role, 2*role+1} ----
  {
    const int e = t >> 2, role = t & 3;
    float Fv[2][NI];
    #pragma unroll
    for (int vv=0; vv<2; ++vv)
      #pragma unroll
      for (int mi=0; mi<NI; ++mi)
        Fv[vv][mi] = __bfloat162float(sF[e*74 + FO + (role*2+vv)*NI + mi]);
    float tmp[2][NO];
    #pragma unroll
    for (int vv=0; vv<2; ++vv)
      #pragma unroll
      for (int o=0; o<NO; ++o) tmp[vv][o] = 0.f;
    #pragma unroll
    for (int o=0; o<NO; ++o)
      #pragma unroll
      for (int mi=0; mi<NI; ++mi){
        float kvv = sKV[e*26 + o*NI + mi];
        #pragma unroll
        for (int vv=0; vv<2; ++vv) tmp[vv][o] += kvv * Fv[vv][mi];
      }
    #pragma unroll
    for (int u=0; u<8; ++u)
      #pragma unroll
      for (int vv=0; vv<2; ++vv){
        float r = sRt[(u*8 + role*2 + vv)*RTP + e];
        #pragma unroll
        for (int o=0; o<NO; ++o) acc[u][AO+o] += r * tmp[vv][o];
      }
  }
}

__global__ __launch_bounds__(256,2) void fused_kernel(
    const float* __restrict__ feats, const int* __restrict__ ei,
    const float* __restrict__ rsh, const __hip_bfloat16* __restrict__ h_bf,
    const __hip_bfloat16* __restrict__ W3t, const float* __restrict__ C3g,
    float* __restrict__ msg, int E)
{
  __shared__ __align__(16) char smem[SMEM_SZ];
  __hip_bfloat16* sH  = (__hip_bfloat16*)(smem + OF_H);
  __hip_bfloat16* sW3 = (__hip_bfloat16*)(smem + OF_W3);
  float* sRt  = (float*)(smem + OF_RT);
  __hip_bfloat16* sF = (__hip_bfloat16*)(smem + OF_F);
  float* sRsh = (float*)(smem + OF_RSH);
  float* sKV  = (float*)(smem + OF_KV);
  float* sC3  = (float*)(smem + OF_C3);
  int*   sSrc = (int*)(smem + OF_SRC);

  const int t = threadIdx.x;
  const int eb = blockIdx.x*64;

  // ---- prologue staging ----
  {
    const float4* g = (const float4*)(h_bf + (size_t)eb*136);
    float4* s = (float4*)sH;
    for (int p=t; p<1088; p+=256) s[p] = g[p];
  }
  for (int p=t; p<64; p+=256){
    int e = eb + p;
    sSrc[p] = (e < E) ? ei[e] : 0;
  }
  for (int p=t; p<1600; p+=256){
    int el = p/25, j = p%25;
    int e = eb + el;
    sRsh[el*26 + j] = (e < E) ? rsh[(size_t)e*25 + j] : 0.f;
  }
  for (int p=t; p<C3TOT; p+=256) sC3[p] = C3g[p];
  __syncthreads();
  for (int p=t; p<64*72; p+=256){
    int el = p/72, j = p%72;
    sF[el*74 + j] = __float2bfloat16(feats[(size_t)sSrc[el]*72 + j]);
  }

  float acc[8][9];
  #pragma unroll
  for (int u=0; u<8; ++u)
    #pragma unroll
    for (int j=0; j<9; ++j) acc[u][j] = 0.f;

  // ---- 19 phases (chunk order = CB tables) ----
  phase<0,0,0>( 0, W3t, sH, sW3, sRt, sF, sRsh, sKV, sC3, acc, t);
  phase<0,1,1>( 1, W3t, sH, sW3, sRt, sF, sRsh, sKV, sC3, acc, t);
  phase<0,2,2>( 2, W3t, sH, sW3, sRt, sF, sRsh, sKV, sC3, acc, t);
  phase<1,0,1>( 3, W3t, sH, sW3, sRt, sF, sRsh, sKV, sC3, acc, t);
  phase<1,1,0>( 4, W3t, sH, sW3, sRt, sF, sRsh, sKV, sC3, acc, t);
  phase<1,1,1>( 5, W3t, sH, sW3, sRt, sF, sRsh, sKV, sC3, acc, t);
  phase<1,1,2>( 6, W3t, sH, sW3, sRt, sF, sRsh, sKV, sC3, acc, t);
  phase<1,2,1>( 7, W3t, sH, sW3, sRt, sF, sRsh, sKV, sC3, acc, t);
  phase<1,2,2>( 8, W3t, sH, sW3, sRt, sF, sRsh, sKV, sC3, acc, t);
  phase<1,2,3>( 9, W3t, sH, sW3, sRt, sF, sRsh, sKV, sC3, acc, t);
  phase<2,0,2>(10, W3t, sH, sW3, sRt, sF, sRsh, sKV, sC3, acc, t);
  phase<2,1,1>(11, W3t, sH, sW3, sRt, sF, sRsh, sKV, sC3, acc, t);
  phase<2,1,2>(12, W3t, sH, sW3, sRt, sF, sRsh, sKV, sC3, acc, t);
  phase<2,1,3>(13, W3t, sH, sW3, sRt, sF, sRsh, sKV, sC3, acc, t);
  phase<2,2,0>(14, W3t, sH, sW3, sRt, sF, sRsh, sKV, sC3, acc, t);
  phase<2,2,1>(15, W3t, sH, sW3, sRt, sF, sRsh, sKV, sC3, acc, t);
  phase<2,2,2>(16, W3t, sH, sW3, sRt, sF, sRsh, sKV, sC3, acc, t);
  phase<2,2,3>(17, W3t, sH, sW3, sRt, sF, sRsh, sKV, sC3, acc, t);
  phase<2,2,4>(18, W3t, sH, sW3, sRt, sF, sRsh, sKV, sC3, acc, t);

  // ---- quad merge (lanes 4k..4k+3 share an edge) ----
  #pragma unroll
  for (int u=0; u<8; ++u)
    #pragma unroll
    for (int j=0; j<9; ++j){
      acc[u][j] += __shfl_xor(acc[u][j], 1, 64);
      acc[u][j] += __shfl_xor(acc[u][j], 2, 64);
    }

  // ---- epilogue: scatter into LDS row buffer (aliases dead sH/sW3), then
  //      stream out coalesced float4s (full cachelines) ----
  float* sMsg = (float*)smem;    // 64*72 f32 = 18432 B over sH+sW3
  {
    const int e = t >> 2, role = t & 3;
    float* dst = sMsg + e*72;
    #pragma unroll
    for (int du=0; du<2; ++du){
      int u = role*2 + du;
      dst[u] = acc[u][0]*0.72360125f;                       // lo=0: sqrt(pi/6)
      #pragma unroll
      for (int o=0; o<3; ++o)
        dst[8 + u*3 + o] = acc[u][1+o]*0.8204867f;          // lo=1: sqrt(3pi/14)
      #pragma unroll
      for (int o=0; o<5; ++o)
        dst[32 + u*5 + o] = acc[u][4+o]*0.9341652f;         // lo=2: sqrt(5pi/18)
    }
  }
  __syncthreads();
  {
    const float4* sm = (const float4*)sMsg;
    float4* gm = (float4*)(msg + (size_t)eb*FEATD);
    for (int p=t; p<1152; p+=256) gm[p] = sm[p];
  }
}

// ---------------------------------------------------------------------------
extern "C" void kernel_launch(void* const* d_in, const int* in_sizes, int n_in,
                              void* d_out, int out_size, void* d_ws, size_t ws_size,
                              hipStream_t stream)
{
  const float* feats = (const float*)d_in[0];
  const int*   ei    = (const int*)d_in[1];
  const float* radii = (const float*)d_in[2];
  const float* rsh   = (const float*)d_in[3];
  const float* W0    = (const float*)d_in[4];
  const float* W1    = (const float*)d_in[5];
  const float* W2    = (const float*)d_in[6];
  const float* W3    = (const float*)d_in[7];
  float* out = (float*)d_out;
  const int E = in_sizes[2];
  const int N = in_sizes[0]/FEATD;

  const int EPAD = ((E + 63)/64)*64;
  const int NBLK = EPAD/64;

  char* ws = (char*)d_ws;
  size_t off_b = 0;
  float*  C3f = (float*)(ws + off_b);  off_b += 8192;
  double* Tre = (double*)(ws + off_b); off_b += 12288;
  double* Tim = (double*)(ws + off_b); off_b += 12288;          // 32768
  __hip_bfloat16* W3t  = (__hip_bfloat16*)(ws + off_b); off_b += 335872;  // 368640
  __hip_bfloat16* h_bf = (__hip_bfloat16*)(ws + off_b); off_b += (size_t)EPAD*272;
  float* msg = (float*)(ws + off_b);   off_b += (size_t)EPAD*FEATD*4;
  int* deg    = (int*)(ws + off_b);    off_b += (size_t)N*4;
  int* offv   = (int*)(ws + off_b);    off_b += (size_t)(N+1)*4;
  int* cursor = (int*)(ws + off_b);    off_b += (size_t)N*4;
  int* eid    = (int*)(ws + off_b);    off_b += (size_t)E*4;

  // constants / tables
  c3_build_kernel<<<dim3((C3TOT+63)/64), dim3(64), 0, stream>>>(Tre, Tim);
  c3_norm_kernel<<<dim3(NCOMBO), dim3(64), 0, stream>>>(Tre, Tim, C3f);
  prep_w3t_kernel<<<dim3((1216*136+255)/256), dim3(256), 0, stream>>>(W3, W3t);

  // CSR of edges by target
  hipMemsetAsync(deg, 0, (size_t)N*4, stream);
  hist_kernel<<<dim3((E+255)/256), dim3(256), 0, stream>>>(ei, deg, E);
  scan_kernel<<<dim3(1), dim3(256), 0, stream>>>(deg, offv, cursor, N, E);
  fill_kernel<<<dim3((E+255)/256), dim3(256), 0, stream>>>(ei, cursor, eid, E);

  // main pipeline
  radial_hidden_kernel<<<dim3(NBLK), dim3(256), 0, stream>>>(radii, W0, W1, W2, h_bf, E);
  fused_kernel<<<dim3(NBLK), dim3(256), 0, stream>>>(feats, ei, rsh, h_bf, W3t, C3f, msg, E);
  gather_kernel<<<dim3(N), dim3(64), 0, stream>>>(msg, offv, eid, out, N);
}

// Round 7
// 694.660 us; speedup vs baseline: 1.0138x; 1.0138x over previous
//
#include <hip/hip_runtime.h>
#include <hip/hip_bf16.h>
#include <math.h>

// ============================================================================
// MinimalNetwork, round 7: fused GEMM+TP with double-buffered W3 staging
// (2 barriers/phase instead of 3), h-fragments held in registers, sRt pitch 67.
//   radial_hidden : h_bf[e][136] bf16 — layer3 staged in LDS, float4 copy-out
//   prep_w3t      : W3t[1216][136] bf16, chunk-major column permutation
//   fused_kernel  : 19 phases: [prefetch W3 chunk k+1 -> other buf | kv=C3*y |
//                   MFMA 64x64 from regs-h] -> sync -> TP consume -> sync.
//   hist/scan/fill: CSR of edges by target node
//   gather_kernel : one wave per node, sums its message rows -> out
// ============================================================================

#define FEATD 72
#define NCOL 1216
#define SWISH_SCALE 1.679177f

typedef __attribute__((ext_vector_type(8))) short bf16x8;
typedef __attribute__((ext_vector_type(4))) float f32x4;

// ---- 19 (lo,li,lf) chunks; CB_OFF = offsets into the C3 coefficient pool ----
constexpr int NCOMBO = 19;
constexpr int CB_LO[NCOMBO] = {0,0,0,1,1,1,1,1,1,1,2,2,2,2,2,2,2,2,2};
constexpr int CB_LI[NCOMBO] = {0,1,2,0,1,1,1,2,2,2,0,1,1,1,2,2,2,2,2};
constexpr int CB_LF[NCOMBO] = {0,1,2,1,0,1,2,1,2,3,2,1,2,3,0,1,2,3,4};
constexpr int CB_OFF[NCOMBO] = {0,1,10,35,44,53,80,125,170,245,350,375,420,495,600,625,700,825,1000};
constexpr int CB_SZ[NCOMBO]  = {1,9,25,9,9,27,45,45,75,105,25,45,75,105,25,75,125,175,225};
constexpr int C3TOT = 1225;

constexpr int C3OFFT[3][3][5] = {
  { {0,-1,-1,-1,-1}, {-1,1,-1,-1,-1}, {-1,-1,10,-1,-1} },
  { {-1,35,-1,-1,-1}, {44,53,80,-1,-1}, {-1,125,170,245,-1} },
  { {-1,-1,350,-1,-1}, {-1,375,420,495,-1}, {600,625,700,825,1000} }
};
constexpr int ROFFT[3][3] = {{0,64,128},{192,256,448},{640,704,896}};
constexpr int FOFFT[3]   = {0,8,32};

__device__ const double d_fact[11] = {1.,1.,2.,6.,24.,120.,720.,5040.,40320.,362880.,3628800.};

// ---------------------------------------------------------------------------
// Wigner 3j (complex basis, Racah) in double precision + real change of basis
// ---------------------------------------------------------------------------
__device__ double w3j_entry(int j1,int j2,int j3,int m1,int m2,int m3){
  if (m1+m2+m3 != 0) return 0.0;
  int dj = j1-j2; if (dj<0) dj=-dj;
  if (j3 < dj || j3 > j1+j2) return 0.0;
  int t1 = j2 - m1 - j3, t2 = j1 + m2 - j3;
  int kmin = 0; if (t1>kmin) kmin=t1; if (t2>kmin) kmin=t2;
  int kmax = j1+j2-j3; if (j1-m1<kmax) kmax=j1-m1; if (j2+m2<kmax) kmax=j2+m2;
  double s = 0.0;
  for (int k=kmin;k<=kmax;++k){
    double den = d_fact[k]*d_fact[k-t1]*d_fact[k-t2]*d_fact[j1+j2-j3-k]
               * d_fact[j1-m1-k]*d_fact[j2+m2-k];
    s += ((k&1)? -1.0:1.0)/den;
  }
  double pref = sqrt(d_fact[j1+j2-j3]*d_fact[j1-j2+j3]*d_fact[-j1+j2+j3]/d_fact[j1+j2+j3+1]
               * d_fact[j1+m1]*d_fact[j1-m1]*d_fact[j2+m2]*d_fact[j2-m2]
               * d_fact[j3+m3]*d_fact[j3-m3]);
  int ex = j1-j2-m3;
  if (ex & 1) pref = -pref;
  return pref*s;
}

__device__ void cob(int l, int r, int c, double& re, double& im){
  re = 0.0; im = 0.0;
  int mr = r - l, mc = c - l;
  const double s = 0.70710678118654752440;
  if (mr == 0) { if (mc == 0) re = 1.0; return; }
  if (mr > 0) {
    if (mc == mr)       re = (mr & 1) ? -s : s;
    else if (mc == -mr) re = s;
  } else {
    int m = -mr;
    if (mc == -m)      im = s;
    else if (mc == m)  im = (m & 1) ? s : -s;
  }
}

__global__ void c3_build_kernel(double* __restrict__ Tre, double* __restrict__ Tim){
  int idx = blockIdx.x*64 + threadIdx.x;
  if (idx >= C3TOT) return;
  int c = 0;
  while (c+1 < NCOMBO && idx >= CB_OFF[c+1]) ++c;
  int lo = CB_LO[c], li = CB_LI[c], lf = CB_LF[c];
  int n2 = 2*li+1, n3 = 2*lf+1;
  int loc = idx - CB_OFF[c];
  int a = loc/(n2*n3), b = (loc/n3)%n2, g = loc%n3;
  double sre=0.0, sim=0.0;
  for (int m1=-lo; m1<=lo; ++m1){
    for (int m2=-li; m2<=li; ++m2){
      int m3 = -m1-m2;
      if (m3 < -lf || m3 > lf) continue;
      double w = w3j_entry(lo,li,lf,m1,m2,m3);
      if (w == 0.0) continue;
      double r1,i1,r2,i2,r3,i3;
      cob(lo, a, m1+lo, r1,i1);
      cob(li, b, m2+li, r2,i2);
      cob(lf, g, m3+lf, r3,i3);
      double rr = r1*r2 - i1*i2, ri = r1*i2 + i1*r2;
      double fr = rr*r3 - ri*i3, fi = rr*i3 + ri*r3;
      sre += fr*w; sim += fi*w;
    }
  }
  Tre[idx] = sre; Tim[idx] = sim;
}

__global__ void c3_norm_kernel(const double* __restrict__ Tre, const double* __restrict__ Tim,
                               float* __restrict__ C3f){
  int c = blockIdx.x;
  int off = CB_OFF[c], sz = CB_SZ[c];
  int t = threadIdx.x;
  double sre=0.0, sim=0.0;
  for (int p=t; p<sz; p+=64){ double x=Tre[off+p], y=Tim[off+p]; sre+=x*x; sim+=y*y; }
  for (int m=1; m<64; m<<=1){ sre += __shfl_xor(sre, m, 64); sim += __shfl_xor(sim, m, 64); }
  bool useRe = (sre >= sim);
  double n = sqrt(useRe ? sre : sim);
  double inv = (n > 0.0) ? 1.0/n : 1.0;
  for (int p=t; p<sz; p+=64){
    double v = useRe ? Tre[off+p] : Tim[off+p];
    C3f[off+p] = (float)(v*inv);
  }
}

// ---------------------------------------------------------------------------
// W3t[c'][k], c' chunk-major: c' = chunk*64 + uv maps to original column
// ROFFT[lo][li] + uv*nlf + fi. 0.1 scale folded. Pitch 136, pad k>=100 = 0.
// ---------------------------------------------------------------------------
__global__ __launch_bounds__(256) void prep_w3t_kernel(const float* __restrict__ W3,
                                                       __hip_bfloat16* __restrict__ W3t){
  int idx = blockIdx.x*256 + threadIdx.x;
  if (idx >= 1216*136) return;
  int cp = idx/136, k = idx%136;
  int chunk = cp>>6, uv = cp&63;
  int lo = CB_LO[chunk], li = CB_LI[chunk], lf = CB_LF[chunk];
  int lmin = lo<li ? lo : li;
  int nlf = 2*lmin+1;
  int fi = lf - (lo>li ? lo-li : li-lo);
  int c = ROFFT[lo][li] + uv*nlf + fi;
  float v = (k < 100) ? 0.1f*W3[(size_t)k*NCOL + c] : 0.f;
  W3t[idx] = __float2bfloat16(v);
}

// ---------------------------------------------------------------------------
// Radial hidden chain -> h_bf[e][136] bf16; layer3 staged in LDS, coalesced out
// ---------------------------------------------------------------------------
__device__ __forceinline__ float swishf(float s){
  return SWISH_SCALE * s / (1.f + __expf(-s));
}

__global__ __launch_bounds__(256) void radial_hidden_kernel(
    const float* __restrict__ radii,
    const float* __restrict__ W0, const float* __restrict__ W1, const float* __restrict__ W2,
    __hip_bfloat16* __restrict__ h_bf, int E)
{
  __shared__ float sW[10000];
  __shared__ __align__(16) float sX[6400];   // [er][k], pitch 100; reused as bf16 staging
  __shared__ float sY[6400];
  __shared__ float sbas[640];
  const int t = threadIdx.x;
  const int et0 = blockIdx.x*64;

  for (int p=t; p<640; p+=256){
    int er = p/10, k = p%10;
    int eg = et0 + er;
    float r = (eg < E) ? radii[eg] : 0.f;
    float c = 0.7f + (2.5f/9.0f)*(float)k;
    float d = (r - c) * (9.0f/2.5f);
    sbas[p] = __expf(-d*d);
  }
  for (int p=t; p<1000; p+=256) sW[p] = W0[p]*0.3162277660168379f; // 1/sqrt(10)
  __syncthreads();
  for (int p=t; p<6400; p+=256){
    int er = p/100, o = p%100;
    float s = 0.f;
    #pragma unroll
    for (int k=0;k<10;++k) s += sbas[er*10+k]*sW[k*100+o];
    sX[p] = swishf(s);
  }
  __syncthreads();
  for (int p=t; p<10000; p+=256) sW[p] = W1[p]*0.1f;
  __syncthreads();
  for (int q=t; q<400; q+=256){
    int erb = (q/25)*4, ob = (q%25)*4;
    float acc[4][4] = {};
    for (int k=0;k<100;++k){
      float4 w = *(const float4*)&sW[k*100+ob];
      #pragma unroll
      for (int i=0;i<4;++i){
        float a = sX[(erb+i)*100+k];
        acc[i][0]+=a*w.x; acc[i][1]+=a*w.y; acc[i][2]+=a*w.z; acc[i][3]+=a*w.w;
      }
    }
    #pragma unroll
    for (int i=0;i<4;++i){
      float4 v = make_float4(swishf(acc[i][0]),swishf(acc[i][1]),swishf(acc[i][2]),swishf(acc[i][3]));
      *(float4*)&sY[(erb+i)*100+ob] = v;
    }
  }
  __syncthreads();   // layer2 done reading sX -> sX reusable as staging
  for (int p=t; p<10000; p+=256) sW[p] = W2[p]*0.1f;
  __syncthreads();

  // layer 3: compute into LDS staging (bf16 [64][136]), then coalesced copy-out
  __hip_bfloat16* sHB = (__hip_bfloat16*)sX;   // 17408 B <= 25600 B
  for (int p=t; p<64*36; p+=256){
    int er = p/36, k = 100 + p%36;
    sHB[er*136 + k] = __float2bfloat16(0.f);
  }
  for (int q=t; q<400; q+=256){
    int erb = (q/25)*4, ob = (q%25)*4;
    float acc[4][4] = {};
    for (int k=0;k<100;++k){
      float4 w = *(const float4*)&sW[k*100+ob];
      #pragma unroll
      for (int i=0;i<4;++i){
        float a = sY[(erb+i)*100+k];
        acc[i][0]+=a*w.x; acc[i][1]+=a*w.y; acc[i][2]+=a*w.z; acc[i][3]+=a*w.w;
      }
    }
    #pragma unroll
    for (int i=0;i<4;++i){
      __hip_bfloat16 hv[4];
      #pragma unroll
      for (int j=0;j<4;++j) hv[j] = __float2bfloat16(swishf(acc[i][j]));
      *(short4*)&sHB[(erb+i)*136 + ob] = *(short4*)hv;
    }
  }
  __syncthreads();
  {
    const float4* sm = (const float4*)sHB;
    float4* gm = (float4*)(h_bf + (size_t)et0*136);
    for (int p=t; p<1088; p+=256) gm[p] = sm[p];
  }
}

// ---------------------------------------------------------------------------
// CSR of edges by target node
// ---------------------------------------------------------------------------
__global__ __launch_bounds__(256) void hist_kernel(const int* __restrict__ ei,
                                                   int* __restrict__ deg, int E){
  int e = blockIdx.x*256 + threadIdx.x;
  if (e < E) atomicAdd(&deg[ei[E+e]], 1);
}

__global__ __launch_bounds__(256) void scan_kernel(const int* __restrict__ deg,
                                                   int* __restrict__ off,
                                                   int* __restrict__ cursor, int N, int E){
  __shared__ int part[256], spref[256];
  const int t = threadIdx.x;
  const int CH = (N + 255)/256;
  int lo = t*CH, hi = lo+CH < N ? lo+CH : N;
  int s = 0;
  for (int n=lo; n<hi; ++n) s += deg[n];
  part[t] = s;
  __syncthreads();
  if (t == 0){
    int run = 0;
    for (int i=0;i<256;++i){ spref[i] = run; run += part[i]; }
  }
  __syncthreads();
  int run = spref[t];
  for (int n=lo; n<hi; ++n){ off[n] = run; cursor[n] = run; run += deg[n]; }
  if (t == 255) off[N] = E;
}

__global__ __launch_bounds__(256) void fill_kernel(const int* __restrict__ ei,
                                                   int* __restrict__ cursor,
                                                   int* __restrict__ eid, int E){
  int e = blockIdx.x*256 + threadIdx.x;
  if (e < E){
    int idx = atomicAdd(&cursor[ei[E+e]], 1);
    eid[idx] = e;
  }
}

// ---------------------------------------------------------------------------
// Gather: one 64-lane wave per node; writes every output element exactly once.
// ---------------------------------------------------------------------------
__global__ __launch_bounds__(64) void gather_kernel(const float* __restrict__ msg,
                                                    const int* __restrict__ off,
                                                    const int* __restrict__ eid,
                                                    float* __restrict__ out, int N){
  const int n = blockIdx.x;
  const int t = threadIdx.x;
  const int s = off[n], e1 = off[n+1];
  float a0 = 0.f, a1 = 0.f;
  for (int i=s; i<e1; ++i){
    const float* m = msg + (size_t)eid[i]*FEATD;
    a0 += m[t];
    if (t < 8) a1 += m[64+t];
  }
  out[(size_t)n*FEATD + t] = a0;
  if (t < 8) out[(size_t)n*FEATD + 64 + t] = a1;
}

// ---------------------------------------------------------------------------
// Fused GEMM+TP. 256 threads = 4 waves; 64 edges/block; 4 roles/edge.
// Double-buffered W3 staging (2 barriers/phase); h-fragments in registers.
// ---------------------------------------------------------------------------
#define RTP 67   // sRt pitch (odd: role-stride 16 rows -> bank+16 -> 2-way max)

constexpr int OF_W3A = 0;         // 64*136 bf16 = 17408
constexpr int OF_W3B = 17408;     // 64*136 bf16 = 17408
constexpr int OF_RT  = 34816;     // 64*67 f32   = 17152
constexpr int OF_F   = 51968;     // 64*74 bf16  = 9472
constexpr int OF_RSH = 61440;     // 64*26 f32   = 6656
constexpr int OF_KV  = 68096;     // 64*26 f32   = 6656
constexpr int OF_C3  = 74752;     // 1228 f32    = 4912
constexpr int OF_SRC = 79664;     // 64 int      = 256
constexpr int SMEM_SZ = 79920;

template<int LO,int LI,int LF, bool PF>
__device__ __forceinline__ void phase(
    int nextChunk, const __hip_bfloat16* __restrict__ W3t,
    const bf16x8 (&hf)[4],
    __hip_bfloat16* sW3src, __hip_bfloat16* sW3dst, float* sRt,
    __hip_bfloat16* sF, float* sRsh, float* sKV, const float* sC3,
    float (&acc)[8][9], int t)
{
  constexpr int NO = 2*LO+1, NI = 2*LI+1, NF = 2*LF+1;
  constexpr int C3B = C3OFFT[LO][LI][LF];
  constexpr int FO  = FOFFT[LI];
  constexpr int AO  = (LO==0) ? 0 : (LO==1) ? 1 : 4;

  // ---- 1. prefetch next chunk's 64 W3t rows into the other buffer ----
  if (PF){
    const float4* g = (const float4*)(W3t + (size_t)nextChunk*64*136);
    float4* s = (float4*)sW3dst;
    for (int p=t; p<1088; p+=256) s[p] = g[p];
  }
  // ---- 2. cooperative kv[e][o*NI+mi] = sum_mf C3 * y ----
  {
    const int le = t & 63, wv = t >> 6;
    float y[NF];
    #pragma unroll
    for (int mf=0; mf<NF; ++mf) y[mf] = sRsh[le*26 + LF*LF + mf];
    for (int it = wv; it < NO*NI; it += 4){
      float s = 0.f;
      #pragma unroll
      for (int mf=0; mf<NF; ++mf) s += sC3[C3B + it*NF + mf] * y[mf];
      sKV[le*26 + it] = s;
    }
  }
  // ---- 3. MFMA: Rt_chunk[c=uv][e], 64x64, K=128; B-operand from registers ----
  {
    const int lane = t & 63, wv = t >> 6;
    const int lr = lane & 15, lq = lane >> 4;
    f32x4 a4[4] = {};
    #pragma unroll
    for (int ks=0; ks<4; ++ks){
      #pragma unroll
      for (int ct=0; ct<4; ++ct){
        bf16x8 a = *(const bf16x8*)&sW3src[(ct*16+lr)*136 + ks*32 + lq*8];
        a4[ct] = __builtin_amdgcn_mfma_f32_16x16x32_bf16(a, hf[ks], a4[ct], 0, 0, 0);
      }
    }
    #pragma unroll
    for (int ct=0; ct<4; ++ct)
      #pragma unroll
      for (int r=0; r<4; ++r)
        sRt[(ct*16 + lq*4 + r)*RTP + wv*16 + lr] = a4[ct][r];
  }
  __syncthreads();   // sRt + sKV + prefetched W3 visible

  // ---- 4. TP consume: 4 roles/edge, role handles v in {2*role, 2*role+1} ----
  {
    const int e = t >> 2, role = t & 3;
    float Fv[2][NI];
    #pragma unroll
    for (int vv=0; vv<2; ++vv)
      #pragma unroll
      for (int mi=0; mi<NI; ++mi)
        Fv[vv][mi] = __bfloat162float(sF[e*74 + FO + (role*2+vv)*NI + mi]);
    float tmp[2][NO];
    #pragma unroll
    for (int vv=0; vv<2; ++vv)
      #pragma unroll
      for (int o=0; o<NO; ++o) tmp[vv][o] = 0.f;
    #pragma unroll
    for (int o=0; o<NO; ++o)
      #pragma unroll
      for (int mi=0; mi<NI; ++mi){
        float kvv = sKV[e*26 + o*NI + mi];
        #pragma unroll
        for (int vv=0; vv<2; ++vv) tmp[vv][o] += kvv * Fv[vv][mi];
      }
    #pragma unroll
    for (int u=0; u<8; ++u)
      #pragma unroll
      for (int vv=0; vv<2; ++vv){
        float r = sRt[(u*8 + role*2 + vv)*RTP + e];
        #pragma unroll
        for (int o=0; o<NO; ++o) acc[u][AO+o] += r * tmp[vv][o];
      }
  }
  __syncthreads();   // consume done: sRt/sKV free; src buffer free for prefetch
}

__global__ __launch_bounds__(256,2) void fused_kernel(
    const float* __restrict__ feats, const int* __restrict__ ei,
    const float* __restrict__ rsh, const __hip_bfloat16* __restrict__ h_bf,
    const __hip_bfloat16* __restrict__ W3t, const float* __restrict__ C3g,
    float* __restrict__ msg, int E)
{
  __shared__ __align__(16) char smem[SMEM_SZ];
  __hip_bfloat16* sW3A = (__hip_bfloat16*)(smem + OF_W3A);
  __hip_bfloat16* sW3B = (__hip_bfloat16*)(smem + OF_W3B);
  float* sRt  = (float*)(smem + OF_RT);
  __hip_bfloat16* sF = (__hip_bfloat16*)(smem + OF_F);
  float* sRsh = (float*)(smem + OF_RSH);
  float* sKV  = (float*)(smem + OF_KV);
  float* sC3  = (float*)(smem + OF_C3);
  int*   sSrc = (int*)(smem + OF_SRC);

  const int t = threadIdx.x;
  const int eb = blockIdx.x*64;

  // ---- h fragments into registers (B-operand, fixed across all 19 phases) ----
  bf16x8 hf[4];
  {
    const int lane = t & 63, wv = t >> 6;
    const int lr = lane & 15, lq = lane >> 4;
    const __hip_bfloat16* hrow = h_bf + (size_t)(eb + wv*16 + lr)*136;
    #pragma unroll
    for (int ks=0; ks<4; ++ks)
      hf[ks] = *(const bf16x8*)&hrow[ks*32 + lq*8];
  }
  // ---- prologue staging ----
  {
    const float4* g = (const float4*)W3t;   // chunk 0
    float4* s = (float4*)sW3A;
    for (int p=t; p<1088; p+=256) s[p] = g[p];
  }
  for (int p=t; p<64; p+=256){
    int e = eb + p;
    sSrc[p] = (e < E) ? ei[e] : 0;
  }
  for (int p=t; p<1600; p+=256){
    int el = p/25, j = p%25;
    int e = eb + el;
    sRsh[el*26 + j] = (e < E) ? rsh[(size_t)e*25 + j] : 0.f;
  }
  for (int p=t; p<C3TOT; p+=256) sC3[p] = C3g[p];
  __syncthreads();
  for (int p=t; p<64*72; p+=256){
    int el = p/72, j = p%72;
    sF[el*74 + j] = __float2bfloat16(feats[(size_t)sSrc[el]*72 + j]);
  }
  // (sF consumed only after phase 0's mid-phase barrier — no extra sync needed)

  float acc[8][9];
  #pragma unroll
  for (int u=0; u<8; ++u)
    #pragma unroll
    for (int j=0; j<9; ++j) acc[u][j] = 0.f;

  // ---- 19 phases, alternating W3 buffers (chunk k reads buf[k&1]) ----
  phase<0,0,0,true >( 1, W3t, hf, sW3A, sW3B, sRt, sF, sRsh, sKV, sC3, acc, t);
  phase<0,1,1,true >( 2, W3t, hf, sW3B, sW3A, sRt, sF, sRsh, sKV, sC3, acc, t);
  phase<0,2,2,true >( 3, W3t, hf, sW3A, sW3B, sRt, sF, sRsh, sKV, sC3, acc, t);
  phase<1,0,1,true >( 4, W3t, hf, sW3B, sW3A, sRt, sF, sRsh, sKV, sC3, acc, t);
  phase<1,1,0,true >( 5, W3t, hf, sW3A, sW3B, sRt, sF, sRsh, sKV, sC3, acc, t);
  phase<1,1,1,true >( 6, W3t, hf, sW3B, sW3A, sRt, sF, sRsh, sKV, sC3, acc, t);
  phase<1,1,2,true >( 7, W3t, hf, sW3A, sW3B, sRt, sF, sRsh, sKV, sC3, acc, t);
  phase<1,2,1,true >( 8, W3t, hf, sW3B, sW3A, sRt, sF, sRsh, sKV, sC3, acc, t);
  phase<1,2,2,true >( 9, W3t, hf, sW3A, sW3B, sRt, sF, sRsh, sKV, sC3, acc, t);
  phase<1,2,3,true >(10, W3t, hf, sW3B, sW3A, sRt, sF, sRsh, sKV, sC3, acc, t);
  phase<2,0,2,true >(11, W3t, hf, sW3A, sW3B, sRt, sF, sRsh, sKV, sC3, acc, t);
  phase<2,1,1,true >(12, W3t, hf, sW3B, sW3A, sRt, sF, sRsh, sKV, sC3, acc, t);
  phase<2,1,2,true >(13, W3t, hf, sW3A, sW3B, sRt, sF, sRsh, sKV, sC3, acc, t);
  phase<2,1,3,true >(14, W3t, hf, sW3B, sW3A, sRt, sF, sRsh, sKV, sC3, acc, t);
  phase<2,2,0,true >(15, W3t, hf, sW3A, sW3B, sRt, sF, sRsh, sKV, sC3, acc, t);
  phase<2,2,1,true >(16, W3t, hf, sW3B, sW3A, sRt, sF, sRsh, sKV, sC3, acc, t);
  phase<2,2,2,true >(17, W3t, hf, sW3A, sW3B, sRt, sF, sRsh, sKV, sC3, acc, t);
  phase<2,2,3,true >(18, W3t, hf, sW3B, sW3A, sRt, sF, sRsh, sKV, sC3, acc, t);
  phase<2,2,4,false>(19, W3t, hf, sW3A, sW3B, sRt, sF, sRsh, sKV, sC3, acc, t);

  // ---- quad merge (lanes 4k..4k+3 share an edge) ----
  #pragma unroll
  for (int u=0; u<8; ++u)
    #pragma unroll
    for (int j=0; j<9; ++j){
      acc[u][j] += __shfl_xor(acc[u][j], 1, 64);
      acc[u][j] += __shfl_xor(acc[u][j], 2, 64);
    }

  // ---- epilogue: LDS row buffer (aliases dead W3 buffers), coalesced out ----
  float* sMsg = (float*)smem;    // 64*72 f32 = 18432 B over sW3A+sW3B
  {
    const int e = t >> 2, role = t & 3;
    float* dst = sMsg + e*72;
    #pragma unroll
    for (int du=0; du<2; ++du){
      int u = role*2 + du;
      dst[u] = acc[u][0]*0.72360125f;                       // lo=0: sqrt(pi/6)
      #pragma unroll
      for (int o=0; o<3; ++o)
        dst[8 + u*3 + o] = acc[u][1+o]*0.8204867f;          // lo=1: sqrt(3pi/14)
      #pragma unroll
      for (int o=0; o<5; ++o)
        dst[32 + u*5 + o] = acc[u][4+o]*0.9341652f;         // lo=2: sqrt(5pi/18)
    }
  }
  __syncthreads();
  {
    const float4* sm = (const float4*)sMsg;
    float4* gm = (float4*)(msg + (size_t)eb*FEATD);
    for (int p=t; p<1152; p+=256) gm[p] = sm[p];
  }
}

// ---------------------------------------------------------------------------
extern "C" void kernel_launch(void* const* d_in, const int* in_sizes, int n_in,
                              void* d_out, int out_size, void* d_ws, size_t ws_size,
                              hipStream_t stream)
{
  const float* feats = (const float*)d_in[0];
  const int*   ei    = (const int*)d_in[1];
  const float* radii = (const float*)d_in[2];
  const float* rsh   = (const float*)d_in[3];
  const float* W0    = (const float*)d_in[4];
  const float* W1    = (const float*)d_in[5];
  const float* W2    = (const float*)d_in[6];
  const float* W3    = (const float*)d_in[7];
  float* out = (float*)d_out;
  const int E = in_sizes[2];
  const int N = in_sizes[0]/FEATD;

  const int EPAD = ((E + 63)/64)*64;
  const int NBLK = EPAD/64;

  char* ws = (char*)d_ws;
  size_t off_b = 0;
  float*  C3f = (float*)(ws + off_b);  off_b += 8192;
  double* Tre = (double*)(ws + off_b); off_b += 12288;
  double* Tim = (double*)(ws + off_b); off_b += 12288;          // 32768
  __hip_bfloat16* W3t  = (__hip_bfloat16*)(ws + off_b); off_b += 335872;  // 368640
  __hip_bfloat16* h_bf = (__hip_bfloat16*)(ws + off_b); off_b += (size_t)EPAD*272;
  float* msg = (float*)(ws + off_b);   off_b += (size_t)EPAD*FEATD*4;
  int* deg    = (int*)(ws + off_b);    off_b += (size_t)N*4;
  int* offv   = (int*)(ws + off_b);    off_b += (size_t)(N+1)*4;
  int* cursor = (int*)(ws + off_b);    off_b += (size_t)N*4;
  int* eid    = (int*)(ws + off_b);    off_b += (size_t)E*4;

  // constants / tables
  c3_build_kernel<<<dim3((C3TOT+63)/64), dim3(64), 0, stream>>>(Tre, Tim);
  c3_norm_kernel<<<dim3(NCOMBO), dim3(64), 0, stream>>>(Tre, Tim, C3f);
  prep_w3t_kernel<<<dim3((1216*136+255)/256), dim3(256), 0, stream>>>(W3, W3t);

  // CSR of edges by target
  hipMemsetAsync(deg, 0, (size_t)N*4, stream);
  hist_kernel<<<dim3((E+255)/256), dim3(256), 0, stream>>>(ei, deg, E);
  scan_kernel<<<dim3(1), dim3(256), 0, stream>>>(deg, offv, cursor, N, E);
  fill_kernel<<<dim3((E+255)/256), dim3(256), 0, stream>>>(ei, cursor, eid, E);

  // main pipeline
  radial_hidden_kernel<<<dim3(NBLK), dim3(256), 0, stream>>>(radii, W0, W1, W2, h_bf, E);
  fused_kernel<<<dim3(NBLK), dim3(256), 0, stream>>>(feats, ei, rsh, h_bf, W3t, C3f, msg, E);
  gather_kernel<<<dim3(N), dim3(64), 0, stream>>>(msg, offv, eid, out, N);
}